// Round 2
// baseline (221.816 us; speedup 1.0000x reference)
//
#include <hip/hip_runtime.h>

#define UU 2048
#define DM 32
#define TB 128   // tile edge / strip height
#define NB 16    // batch
#define NP 3     // pairs
#define NT (UU / TB)        // 16 j-tiles per strip
#define ASZ (NB * UU * DM)  // elements per split array = 1,048,576

// workspace layout (float offsets)
#define WS_S1 0
#define WS_S2 (NP * NB * UU)                 // 98304
#define WS_OO (2 * NP * NB * UU)             // 196608
#define WS_CCA (WS_OO + NP * NB * 2 * DM)    // 199680
#define WS_ZERO_F4 (WS_CCA / 4)              // 49920 float4 (S1,S2,OO zeroed)
#define WS_SPLIT 204800                      // ushort split arrays start here
// total ws bytes = 204800*4 + 6*ASZ*2 = 13,402,112 (~12.8 MB) — required.

typedef short short8_t __attribute__((ext_vector_type(8)));
typedef float float4_t __attribute__((ext_vector_type(4)));

#if __has_builtin(__builtin_amdgcn_exp2f)
#define EXP2(x) __builtin_amdgcn_exp2f(x)
#else
#define EXP2(x) exp2f(x)
#endif

// sqrt(log2(e)): scaling BOTH operands by this makes the MFMA dot equal
// log2(e) * (f1.f2), so exp(dot) == 2^(mfma result).
#define SQRT_LOG2E 1.2011224087864498f

__device__ inline void async16(void* lds, const void* g) {
  __builtin_amdgcn_global_load_lds(
      (const __attribute__((address_space(1))) unsigned int*)g,
      (__attribute__((address_space(3))) unsigned int*)lds, 16, 0, 0);
}

// split scaled x into bf16 hi (truncate) + bf16 lo (truncate of remainder).
__device__ inline void split8s(const float4 x0, const float4 x1, short8_t& h,
                               short8_t& lo) {
  float xs[8] = {x0.x, x0.y, x0.z, x0.w, x1.x, x1.y, x1.z, x1.w};
#pragma unroll
  for (int i = 0; i < 8; ++i) {
    float xv = xs[i] * SQRT_LOG2E;
    unsigned u = __float_as_uint(xv);
    h[i] = (short)(u >> 16);
    float hif = __uint_as_float(u & 0xffff0000u);
    lo[i] = (short)(__float_as_uint(xv - hif) >> 16);
  }
}

// ---------------------------------------------------------------------------
// Stage 0: one-time f32 -> (hi,lo) bf16 split of all three embeddings,
// scaled by sqrt(log2 e). Also zeroes the S1/S2/OO atomic accumulators.
// Layout: H + arr*2*ASZ = hi[16][2048][32], +ASZ = lo.  arr: 0=a 1=v 2=l.
// ---------------------------------------------------------------------------
__global__ __launch_bounds__(256) void stage0_prep(
    const float* __restrict__ a, const float* __restrict__ v,
    const float* __restrict__ l, float* __restrict__ ws) {
  const int gid = blockIdx.x * 256 + threadIdx.x;  // 0..393215
  if (gid < WS_ZERO_F4) ((float4*)ws)[gid] = make_float4(0.f, 0.f, 0.f, 0.f);

  const int per = ASZ / 8;  // 131072 threads per input array
  const int arr = (gid >= per) + (gid >= 2 * per);  // uniform per block
  const float* src = (arr == 0) ? a : (arr == 1) ? v : l;
  const int loc = gid - arr * per;
  const float4* sp = (const float4*)(src + (size_t)loc * 8);
  float4 x0 = sp[0], x1 = sp[1];
  short8_t h, lo;
  split8s(x0, x1, h, lo);
  unsigned short* hq =
      (unsigned short*)(ws + WS_SPLIT) + (size_t)arr * 2 * ASZ + (size_t)loc * 8;
  *(short8_t*)hq = h;
  *(short8_t*)(hq + ASZ) = lo;
}

// ---------------------------------------------------------------------------
// Stage 1 (MFMA bf16x3, strip-pipelined): block = (z, i-strip of 128 rows),
// sweeps all 16 j-tiles with a 3-buffer global_load_lds ring + counted
// vmcnt(4) (never 0 in-loop) + raw s_barrier.  S2 row sums are strip-
// exclusive -> plain stores.  S1 col sums via per-tile rotated atomics
// (jt = (strip+k)&15 so concurrent strips hit disjoint j-ranges).
// XCD swizzle: 6 z per XCD, all 16 strips of a z on one XCD (L2-resident).
// C/D layout: col=lane&15, row=(lane>>4)*4+reg  [m89-verified].
// ---------------------------------------------------------------------------
__global__ __launch_bounds__(256, 3) void stage1_sums(
    const unsigned short* __restrict__ H, float* __restrict__ S1,
    float* __restrict__ S2) {
  const int lid = blockIdx.x;          // 0..767 (768 % 8 == 0, bijective)
  const int xcd = lid & 7;
  const int r6 = lid >> 3;             // 0..95
  const int z = xcd * 6 + (r6 >> 4);   // 0..47 = p*16+b
  const int strip = r6 & 15;
  const int p = z >> 4, b = z & 15;
  const int i0 = strip * TB;

  const int a1 = (p == 2) ? 1 : 0;  // p0:(a,v) p1:(a,l) p2:(v,l)
  const int a2 = (p == 0) ? 1 : 2;
  const unsigned short* f1h = H + (size_t)a1 * 2 * ASZ + (size_t)b * UU * DM;
  const unsigned short* f2h = H + (size_t)a2 * 2 * ASZ + (size_t)b * UU * DM;

  __shared__ __align__(16) unsigned short Bbuf[3][2][TB][DM];  // 48 KiB ring
  __shared__ float ldsC[4][TB];

  const int t = threadIdx.x;
  const int lane = t & 63, w = t >> 6;
  const int lm = lane & 15, lq = lane >> 4, k0 = lq * 8;

  // A fragments (hi+lo) once, straight global->VGPR (permuted-contiguous).
  short8_t a_h[2], a_l[2];
  {
    const unsigned short* ar = f1h + (size_t)(i0 + w * 32 + lm) * DM + k0;
    a_h[0] = *(const short8_t*)ar;
    a_h[1] = *(const short8_t*)(ar + 16 * DM);
    a_l[0] = *(const short8_t*)(ar + ASZ);
    a_l[1] = *(const short8_t*)(ar + ASZ + 16 * DM);
  }

  float rowp[2][4];
#pragma unroll
  for (int rt = 0; rt < 2; ++rt)
#pragma unroll
    for (int r = 0; r < 4; ++r) rowp[rt][r] = 0.f;

  const size_t base = (size_t)z * UU;

  // wave w stages rows [w*32, w*32+32) of hi and lo: 4 async16 per wave.
  auto stageB = [&](int buf, int jt) {
    const unsigned short* gh = f2h + (size_t)(jt * TB + w * 32) * DM + lane * 8;
    async16(&Bbuf[buf][0][w * 32][0], gh);
    async16(&Bbuf[buf][0][w * 32 + 16][0], gh + 16 * DM);
    async16(&Bbuf[buf][1][w * 32][0], gh + ASZ);
    async16(&Bbuf[buf][1][w * 32 + 16][0], gh + ASZ + 16 * DM);
  };

  auto compute = [&](int buf, int jt) {
    float colp[8];
#pragma unroll
    for (int ct = 0; ct < 8; ++ct) colp[ct] = 0.f;
#pragma unroll
    for (int ct = 0; ct < 8; ++ct) {
      short8_t b_h = *(const short8_t*)&Bbuf[buf][0][ct * 16 + lm][k0];
      short8_t b_l = *(const short8_t*)&Bbuf[buf][1][ct * 16 + lm][k0];
#pragma unroll
      for (int rt = 0; rt < 2; ++rt) {
        float4_t c = {0.f, 0.f, 0.f, 0.f};
        c = __builtin_amdgcn_mfma_f32_16x16x32_bf16(a_h[rt], b_h, c, 0, 0, 0);
        c = __builtin_amdgcn_mfma_f32_16x16x32_bf16(a_h[rt], b_l, c, 0, 0, 0);
        c = __builtin_amdgcn_mfma_f32_16x16x32_bf16(a_l[rt], b_h, c, 0, 0, 0);
        float e0 = EXP2(c[0]);
        float e1 = EXP2(c[1]);
        float e2 = EXP2(c[2]);
        float e3 = EXP2(c[3]);
        rowp[rt][0] += e0;
        rowp[rt][1] += e1;
        rowp[rt][2] += e2;
        rowp[rt][3] += e3;
        colp[ct] += (e0 + e1) + (e2 + e3);
      }
    }
    // col (j) sums: reduce across row-quarters, then across waves via LDS
#pragma unroll
    for (int ct = 0; ct < 8; ++ct) {
      float vv = colp[ct];
      vv += __shfl_xor(vv, 16, 64);
      vv += __shfl_xor(vv, 32, 64);
      if (lane < 16) ldsC[w][ct * 16 + lane] = vv;
    }
    asm volatile("s_waitcnt lgkmcnt(0)" ::: "memory");
    __builtin_amdgcn_s_barrier();
    asm volatile("" ::: "memory");
    if (t < TB) {
      float s = ldsC[0][t] + ldsC[1][t] + ldsC[2][t] + ldsC[3][t];
      atomicAdd(&S1[base + jt * TB + t], s);
    }
  };

  stageB(0, strip & 15);
  stageB(1, (strip + 1) & 15);

  int cur = 0;
#pragma unroll 3
  for (int k = 0; k < NT - 1; ++k) {
    // tile k's 4 loads are the oldest outstanding; leave tile k+1's in flight
    asm volatile("s_waitcnt vmcnt(4)" ::: "memory");
    __builtin_amdgcn_s_barrier();
    asm volatile("" ::: "memory");
    if (k < NT - 2) {
      int nb = cur + 2;
      if (nb >= 3) nb -= 3;
      stageB(nb, (strip + k + 2) & 15);
    }
    compute(cur, (strip + k) & 15);
    cur = (cur == 2) ? 0 : cur + 1;
  }
  asm volatile("s_waitcnt vmcnt(0)" ::: "memory");
  __builtin_amdgcn_s_barrier();
  asm volatile("" ::: "memory");
  compute(cur, (strip + NT - 1) & 15);

  // S2 row sums: strip-exclusive -> plain store (no atomics).
#pragma unroll
  for (int rt = 0; rt < 2; ++rt)
#pragma unroll
    for (int r = 0; r < 4; ++r) {
      float vv = rowp[rt][r];
      vv += __shfl_xor(vv, 1, 64);
      vv += __shfl_xor(vv, 2, 64);
      vv += __shfl_xor(vv, 4, 64);
      vv += __shfl_xor(vv, 8, 64);
      if (lm == 0) S2[base + i0 + w * 32 + rt * 16 + lq * 4 + r] = vv;
    }
}

// ---------------------------------------------------------------------------
// Stage 2: per (pair, b, dir, chunk-of-256-rows) accumulate the 32-vector
//   dir0: O1 += sum_j exp(f1_0 . f2_j)/S1[j] * f2_j
//   dir1: O2 += sum_i exp(f1_i . f2_0)/S2[i] * f1_i
// ---------------------------------------------------------------------------
__global__ __launch_bounds__(256) void stage2_O(
    const float* __restrict__ a, const float* __restrict__ v,
    const float* __restrict__ l, const float* __restrict__ S1,
    const float* __restrict__ S2, float* __restrict__ OO) {
  const int idx = blockIdx.x;
  const int chunk = idx & 7;
  const int pd = idx >> 3;
  const int dir = pd & 1;
  const int pb = pd >> 1;
  const int p = pb >> 4, b = pb & 15;
  const float* f1 = (p == 2) ? v : a;
  const float* f2 = (p == 0) ? v : l;
  f1 += (size_t)b * UU * DM;
  f2 += (size_t)b * UU * DM;
  const float* qrow = (dir == 0) ? f1 : f2;
  const float* rows = (dir == 0) ? f2 : f1;
  const float* den = ((dir == 0) ? S1 : S2) + (size_t)pb * UU;

  __shared__ float qv[DM];
  __shared__ __align__(16) float rowsL[256 * 36];  // pad 36 -> bank-free
  __shared__ float wL[256];
  __shared__ float wred[8][DM];
  const int t = threadIdx.x;
  if (t < DM) qv[t] = qrow[t];
  __syncthreads();

  const int r = chunk * 256 + t;
  const float4* rp = (const float4*)(rows + (size_t)r * DM);
  float dot = 0.f;
#pragma unroll
  for (int qq = 0; qq < 8; ++qq) {
    float4 x = rp[qq];
    *(float4*)&rowsL[t * 36 + qq * 4] = x;
    dot = fmaf(x.x, qv[4 * qq + 0], dot);
    dot = fmaf(x.y, qv[4 * qq + 1], dot);
    dot = fmaf(x.z, qv[4 * qq + 2], dot);
    dot = fmaf(x.w, qv[4 * qq + 3], dot);
  }
  wL[t] = __expf(dot) / den[r];
  __syncthreads();

  const int d = t & 31, sl = t >> 5;
  float acc = 0.f;
#pragma unroll
  for (int k = 0; k < 32; ++k) {
    const int rr = sl * 32 + k;
    acc = fmaf(wL[rr], rowsL[rr * 36 + d], acc);
  }
  wred[sl][d] = acc;
  __syncthreads();
  if (t < DM) {
    float o = 0.f;
#pragma unroll
    for (int s2 = 0; s2 < 8; ++s2) o += wred[s2][t];
    atomicAdd(&OO[(size_t)pd * DM + t], o);
  }
}

// ---------------------------------------------------------------------------
// Stage 3 (1024 threads, one block): Bi = OO*qrow; Ci = tanh(Bi@fc1^T+b)@fc2^T;
// alpha = softmax over batch; CCA[b,:] = sum_k alpha[b,k]*Bi[b,k,:]
// ---------------------------------------------------------------------------
__global__ __launch_bounds__(1024) void stage3_head(
    const float* __restrict__ a, const float* __restrict__ v,
    const float* __restrict__ l, const float* __restrict__ OO,
    const float* __restrict__ fc1w, const float* __restrict__ fc1b,
    const float* __restrict__ fc2w, float* __restrict__ CCA) {
  const int t = threadIdx.x;
  __shared__ float BiL[NB * NP * 64];
  __shared__ float CiS[NB * NP];
  __shared__ float denomk[NP];
  __shared__ float fwL[64 * 65];

#pragma unroll
  for (int it = 0; it < 4; ++it) {
    int m = it * 1024 + t;
    fwL[(m >> 6) * 65 + (m & 63)] = fc1w[m];
  }

#pragma unroll
  for (int iter = 0; iter < 3; ++iter) {
    int m = iter * 1024 + t;  // 0..3071
    int bk = m >> 6;          // b*NP + p
    int h = m & 63;
    int b = bk / NP, p = bk - b * NP;
    int dir = h >> 5, hd = h & 31;
    const float* base = (dir == 0) ? ((p == 2) ? v : a) : ((p == 0) ? v : l);
    float q = base[(size_t)b * UU * DM + hd];
    int pb = p * NB + b;
    BiL[bk * 64 + h] = OO[(pb * 2 + dir) * DM + hd] * q;
  }
  __syncthreads();

  const int h = t & 63;
  const int g = t >> 6;  // 0..15
#pragma unroll
  for (int iter = 0; iter < 3; ++iter) {
    int bk = g + 16 * iter;
    float x = fc1b[h];
#pragma unroll 8
    for (int c = 0; c < 64; ++c)
      x = fmaf(BiL[bk * 64 + c], fwL[h * 65 + c], x);
    float vv = tanhf(x) * fc2w[h];
#pragma unroll
    for (int off = 32; off > 0; off >>= 1) vv += __shfl_down(vv, off, 64);
    if (h == 0) CiS[bk] = vv;
  }
  __syncthreads();

  if (t < NP) {
    float s = 0.f;
    for (int b = 0; b < NB; ++b) s += __expf(CiS[b * NP + t]);
    denomk[t] = s;
  }
  __syncthreads();

  {
    int b = g;
    float s = 0.f;
#pragma unroll
    for (int k = 0; k < NP; ++k)
      s += __expf(CiS[b * NP + k]) / denomk[k] * BiL[(b * NP + k) * 64 + h];
    CCA[b * 64 + h] = s;
  }
}

// ---------------------------------------------------------------------------
// Stage 4: broadcast CCA[b,:] to out[b, u, :] for all u.  float4 stores.
// ---------------------------------------------------------------------------
__global__ __launch_bounds__(256) void stage4_bcast(
    const float* __restrict__ CCA, float4* __restrict__ out) {
  const int gid = blockIdx.x * 256 + threadIdx.x;  // 0 .. 524287
  const int c4 = gid & 15;
  const int b = gid >> 15;
  const float4* cc = (const float4*)CCA;
  out[gid] = cc[b * 16 + c4];
}

extern "C" void kernel_launch(void* const* d_in, const int* in_sizes, int n_in,
                              void* d_out, int out_size, void* d_ws,
                              size_t ws_size, hipStream_t stream) {
  const float* a = (const float*)d_in[0];
  const float* v = (const float*)d_in[1];
  const float* l = (const float*)d_in[2];
  const float* fc1w = (const float*)d_in[3];
  const float* fc1b = (const float*)d_in[4];
  const float* fc2w = (const float*)d_in[5];
  float* out = (float*)d_out;

  float* ws = (float*)d_ws;
  float* S1 = ws + WS_S1;
  float* S2 = ws + WS_S2;
  float* OO = ws + WS_OO;
  float* CCA = ws + WS_CCA;
  const unsigned short* H = (const unsigned short*)(ws + WS_SPLIT);

  stage0_prep<<<dim3(1536), 256, 0, stream>>>(a, v, l, ws);
  stage1_sums<<<dim3(NP * NB * NT), 256, 0, stream>>>(H, S1, S2);
  stage2_O<<<dim3(NP * NB * 2 * 8), 256, 0, stream>>>(a, v, l, S1, S2, OO);
  stage3_head<<<dim3(1), 1024, 0, stream>>>(a, v, l, OO, fc1w, fc1b, fc2w,
                                            CCA);
  stage4_bcast<<<dim3(2048), 256, 0, stream>>>(CCA, (float4*)out);
}

// Round 3
// 147.067 us; speedup vs baseline: 1.5083x; 1.5083x over previous
//
#include <hip/hip_runtime.h>

#define UU 2048
#define DM 32
#define TB 128   // tile edge / strip height
#define NB 16    // batch
#define NP 3     // pairs
#define NT (UU / TB)        // 16 j-tiles per strip sweep
#define NSTRIP 16           // strips per z
#define ASZ (NB * UU * DM)  // elements per split array = 1,048,576

// workspace layout (float offsets)
#define WS_S1 0                              // (unused now, kept for layout)
#define WS_S2 (NP * NB * UU)                 // 98304
#define WS_OO (2 * NP * NB * UU)             // 196608
#define WS_CCA (WS_OO + NP * NB * 2 * DM)    // 199680
#define WS_SPLIT 204800                      // ushort split arrays start here
// total ws bytes = 204800*4 + 6*ASZ*2 = 13,402,112 (~12.8 MB) — required.
// S1 per-strip partials (48*16*2048 floats = 6 MB) live in d_out (8.4 MB),
// which stage4 fully overwrites afterwards.

typedef short short8_t __attribute__((ext_vector_type(8)));
typedef float float4_t __attribute__((ext_vector_type(4)));

#if __has_builtin(__builtin_amdgcn_exp2f)
#define EXP2(x) __builtin_amdgcn_exp2f(x)
#else
#define EXP2(x) exp2f(x)
#endif

// sqrt(log2(e)): scaling BOTH operands by this makes the MFMA dot equal
// log2(e) * (f1.f2), so exp(dot) == 2^(mfma result).
#define SQRT_LOG2E 1.2011224087864498f

__device__ inline void async16(void* lds, const void* g) {
  __builtin_amdgcn_global_load_lds(
      (const __attribute__((address_space(1))) unsigned int*)g,
      (__attribute__((address_space(3))) unsigned int*)lds, 16, 0, 0);
}

// split scaled x into bf16 hi (truncate) + bf16 lo (truncate of remainder).
__device__ inline void split8s(const float4 x0, const float4 x1, short8_t& h,
                               short8_t& lo) {
  float xs[8] = {x0.x, x0.y, x0.z, x0.w, x1.x, x1.y, x1.z, x1.w};
#pragma unroll
  for (int i = 0; i < 8; ++i) {
    float xv = xs[i] * SQRT_LOG2E;
    unsigned u = __float_as_uint(xv);
    h[i] = (short)(u >> 16);
    float hif = __uint_as_float(u & 0xffff0000u);
    lo[i] = (short)(__float_as_uint(xv - hif) >> 16);
  }
}

// ---------------------------------------------------------------------------
// Stage 0: one-time f32 -> (hi,lo) bf16 split of all three embeddings,
// scaled by sqrt(log2 e). Also zeroes the OO atomic accumulator.
// Layout: H + arr*2*ASZ = hi[16][2048][32], +ASZ = lo.  arr: 0=a 1=v 2=l.
// ---------------------------------------------------------------------------
__global__ __launch_bounds__(256) void stage0_prep(
    const float* __restrict__ a, const float* __restrict__ v,
    const float* __restrict__ l, float* __restrict__ ws) {
  const int gid = blockIdx.x * 256 + threadIdx.x;  // 0..393215
  if (gid < (NP * NB * 2 * DM) / 4)
    ((float4*)(ws + WS_OO))[gid] = make_float4(0.f, 0.f, 0.f, 0.f);

  const int per = ASZ / 8;  // 131072 threads per input array
  const int arr = (gid >= per) + (gid >= 2 * per);  // uniform per block
  const float* src = (arr == 0) ? a : (arr == 1) ? v : l;
  const int loc = gid - arr * per;
  const float4* sp = (const float4*)(src + (size_t)loc * 8);
  float4 x0 = sp[0], x1 = sp[1];
  short8_t h, lo;
  split8s(x0, x1, h, lo);
  unsigned short* hq =
      (unsigned short*)(ws + WS_SPLIT) + (size_t)arr * 2 * ASZ + (size_t)loc * 8;
  *(short8_t*)hq = h;
  *(short8_t*)(hq + ASZ) = lo;
}

// ---------------------------------------------------------------------------
// Stage 1 (MFMA bf16x3, strip-pipelined, atomic-free): block = (z, i-strip of
// 128 rows), sweeps j-tiles 0..15 IN ORDER (all 16 strips of a z stream the
// same tile concurrently -> 16x L2 multicast). 2-buffer global_load_lds ring,
// counted vmcnt(4) in-loop (drain 0 only on last tile), raw s_barrier.
// Col sums accumulate in an 8 KB LDS array across the sweep; one coalesced
// slab write per block at the end (S1part[z][strip][2048], in d_out).
// S2 row sums are strip-exclusive -> plain stores.
// XCD swizzle: 6 z per XCD (48 = 8*6 bijective), 3 blocks/CU, 768 = 256*3
// all co-resident.  C/D layout: col=lane&15, row=(lane>>4)*4+reg.
// ---------------------------------------------------------------------------
__global__ __launch_bounds__(256, 3) void stage1_sums(
    const unsigned short* __restrict__ H, float* __restrict__ S1part,
    float* __restrict__ S2) {
  const int lid = blockIdx.x;          // 0..767 (768 % 8 == 0)
  const int xcd = lid & 7;
  const int r6 = lid >> 3;             // 0..95
  const int z = xcd * 6 + (r6 >> 4);   // 0..47 = p*16+b
  const int strip = r6 & 15;
  const int p = z >> 4, b = z & 15;
  const int i0 = strip * TB;

  const int a1 = (p == 2) ? 1 : 0;  // p0:(a,v) p1:(a,l) p2:(v,l)
  const int a2 = (p == 0) ? 1 : 2;
  const unsigned short* f1h = H + (size_t)a1 * 2 * ASZ + (size_t)b * UU * DM;
  const unsigned short* f2h = H + (size_t)a2 * 2 * ASZ + (size_t)b * UU * DM;

  __shared__ __align__(16) unsigned short Bbuf[2][2][TB][DM];  // 32 KiB ring
  __shared__ float ldsC[4][TB];                                // 2 KiB
  __shared__ float S1L[UU];                                    // 8 KiB accum

  const int t = threadIdx.x;
  const int lane = t & 63, w = t >> 6;
  const int lm = lane & 15, lq = lane >> 4, k0 = lq * 8;

  // zero the column-sum accumulator
#pragma unroll
  for (int m = 0; m < 8; ++m) S1L[m * 256 + t] = 0.f;

  // A fragments (hi+lo) once, straight global->VGPR (permuted-contiguous).
  short8_t a_h[2], a_l[2];
  {
    const unsigned short* ar = f1h + (size_t)(i0 + w * 32 + lm) * DM + k0;
    a_h[0] = *(const short8_t*)ar;
    a_h[1] = *(const short8_t*)(ar + 16 * DM);
    a_l[0] = *(const short8_t*)(ar + ASZ);
    a_l[1] = *(const short8_t*)(ar + ASZ + 16 * DM);
  }

  float rowp[2][4];
#pragma unroll
  for (int rt = 0; rt < 2; ++rt)
#pragma unroll
    for (int r = 0; r < 4; ++r) rowp[rt][r] = 0.f;

  // wave w stages rows [w*32, w*32+32) of hi and lo: 4 async16 per wave.
  auto stageB = [&](int buf, int jt) {
    const unsigned short* gh = f2h + (size_t)(jt * TB + w * 32) * DM + lane * 8;
    async16(&Bbuf[buf][0][w * 32][0], gh);
    async16(&Bbuf[buf][0][w * 32 + 16][0], gh + 16 * DM);
    async16(&Bbuf[buf][1][w * 32][0], gh + ASZ);
    async16(&Bbuf[buf][1][w * 32 + 16][0], gh + ASZ + 16 * DM);
  };

  auto compute = [&](int buf, int jt) {
    float colp[8];
#pragma unroll
    for (int ct = 0; ct < 8; ++ct) colp[ct] = 0.f;
#pragma unroll
    for (int ct = 0; ct < 8; ++ct) {
      short8_t b_h = *(const short8_t*)&Bbuf[buf][0][ct * 16 + lm][k0];
      short8_t b_l = *(const short8_t*)&Bbuf[buf][1][ct * 16 + lm][k0];
#pragma unroll
      for (int rt = 0; rt < 2; ++rt) {
        float4_t c = {0.f, 0.f, 0.f, 0.f};
        c = __builtin_amdgcn_mfma_f32_16x16x32_bf16(a_h[rt], b_h, c, 0, 0, 0);
        c = __builtin_amdgcn_mfma_f32_16x16x32_bf16(a_h[rt], b_l, c, 0, 0, 0);
        c = __builtin_amdgcn_mfma_f32_16x16x32_bf16(a_l[rt], b_h, c, 0, 0, 0);
        float e0 = EXP2(c[0]);
        float e1 = EXP2(c[1]);
        float e2 = EXP2(c[2]);
        float e3 = EXP2(c[3]);
        rowp[rt][0] += e0;
        rowp[rt][1] += e1;
        rowp[rt][2] += e2;
        rowp[rt][3] += e3;
        colp[ct] += (e0 + e1) + (e2 + e3);
      }
    }
    // col (j) sums: reduce across row-quarters, then across waves via LDS,
    // accumulate into the persistent S1L slab (no atomics).
#pragma unroll
    for (int ct = 0; ct < 8; ++ct) {
      float vv = colp[ct];
      vv += __shfl_xor(vv, 16, 64);
      vv += __shfl_xor(vv, 32, 64);
      if (lane < 16) ldsC[w][ct * 16 + lane] = vv;
    }
    asm volatile("s_waitcnt lgkmcnt(0)" ::: "memory");
    __builtin_amdgcn_s_barrier();
    asm volatile("" ::: "memory");
    if (t < TB)
      S1L[jt * TB + t] += ldsC[0][t] + ldsC[1][t] + ldsC[2][t] + ldsC[3][t];
    // loop-top barrier of the next tile protects ldsC reuse.
  };

  stageB(0, 0);

#pragma unroll 2
  for (int k = 0; k < NT; ++k) {
    if (k + 1 < NT) {
      stageB((k + 1) & 1, k + 1);
      // tile k's 4 loads are the oldest; leave tile k+1's 4 in flight
      asm volatile("s_waitcnt vmcnt(4)" ::: "memory");
    } else {
      asm volatile("s_waitcnt vmcnt(0)" ::: "memory");
    }
    __builtin_amdgcn_s_barrier();
    asm volatile("" ::: "memory");
    compute(k & 1, k);
  }
  __syncthreads();

  // epilogue: one coalesced partial-colsum slab write, plain S2 stores.
  {
    float* dst = S1part + ((size_t)z * NSTRIP + strip) * UU;
#pragma unroll
    for (int m = 0; m < 8; ++m) dst[m * 256 + t] = S1L[m * 256 + t];
  }
  const size_t base = (size_t)z * UU;
#pragma unroll
  for (int rt = 0; rt < 2; ++rt)
#pragma unroll
    for (int r = 0; r < 4; ++r) {
      float vv = rowp[rt][r];
      vv += __shfl_xor(vv, 1, 64);
      vv += __shfl_xor(vv, 2, 64);
      vv += __shfl_xor(vv, 4, 64);
      vv += __shfl_xor(vv, 8, 64);
      if (lm == 0) S2[base + i0 + w * 32 + rt * 16 + lq * 4 + r] = vv;
    }
}

// ---------------------------------------------------------------------------
// Stage 2: per (pair, b, dir, chunk-of-256-rows) accumulate the 32-vector
//   dir0: O1 += sum_j exp(f1_0 . f2_j)/S1[j] * f2_j   (S1 = sum of 16 partials)
//   dir1: O2 += sum_i exp(f1_i . f2_0)/S2[i] * f1_i
// ---------------------------------------------------------------------------
__global__ __launch_bounds__(256) void stage2_O(
    const float* __restrict__ a, const float* __restrict__ v,
    const float* __restrict__ l, const float* __restrict__ S1part,
    const float* __restrict__ S2, float* __restrict__ OO) {
  const int idx = blockIdx.x;
  const int chunk = idx & 7;
  const int pd = idx >> 3;
  const int dir = pd & 1;
  const int pb = pd >> 1;
  const int p = pb >> 4, b = pb & 15;
  const float* f1 = (p == 2) ? v : a;
  const float* f2 = (p == 0) ? v : l;
  f1 += (size_t)b * UU * DM;
  f2 += (size_t)b * UU * DM;
  const float* qrow = (dir == 0) ? f1 : f2;
  const float* rows = (dir == 0) ? f2 : f1;

  __shared__ float qv[DM];
  __shared__ __align__(16) float rowsL[256 * 36];  // pad 36 -> bank-free
  __shared__ float wL[256];
  __shared__ float wred[8][DM];
  const int t = threadIdx.x;
  if (t < DM) qv[t] = qrow[t];
  __syncthreads();

  const int r = chunk * 256 + t;
  const float4* rp = (const float4*)(rows + (size_t)r * DM);
  float dot = 0.f;
#pragma unroll
  for (int qq = 0; qq < 8; ++qq) {
    float4 x = rp[qq];
    *(float4*)&rowsL[t * 36 + qq * 4] = x;
    dot = fmaf(x.x, qv[4 * qq + 0], dot);
    dot = fmaf(x.y, qv[4 * qq + 1], dot);
    dot = fmaf(x.z, qv[4 * qq + 2], dot);
    dot = fmaf(x.w, qv[4 * qq + 3], dot);
  }
  float den;
  if (dir == 0) {
    const float* sp = S1part + (size_t)pb * NSTRIP * UU + r;
    float s = 0.f;
#pragma unroll
    for (int s16 = 0; s16 < NSTRIP; ++s16) s += sp[(size_t)s16 * UU];
    den = s;
  } else {
    den = S2[(size_t)pb * UU + r];
  }
  wL[t] = __expf(dot) / den;
  __syncthreads();

  const int d = t & 31, sl = t >> 5;
  float acc = 0.f;
#pragma unroll
  for (int k = 0; k < 32; ++k) {
    const int rr = sl * 32 + k;
    acc = fmaf(wL[rr], rowsL[rr * 36 + d], acc);
  }
  wred[sl][d] = acc;
  __syncthreads();
  if (t < DM) {
    float o = 0.f;
#pragma unroll
    for (int s2 = 0; s2 < 8; ++s2) o += wred[s2][t];
    atomicAdd(&OO[(size_t)pd * DM + t], o);
  }
}

// ---------------------------------------------------------------------------
// Stage 3 (1024 threads, one block): Bi = OO*qrow; Ci = tanh(Bi@fc1^T+b)@fc2^T;
// alpha = softmax over batch; CCA[b,:] = sum_k alpha[b,k]*Bi[b,k,:]
// ---------------------------------------------------------------------------
__global__ __launch_bounds__(1024) void stage3_head(
    const float* __restrict__ a, const float* __restrict__ v,
    const float* __restrict__ l, const float* __restrict__ OO,
    const float* __restrict__ fc1w, const float* __restrict__ fc1b,
    const float* __restrict__ fc2w, float* __restrict__ CCA) {
  const int t = threadIdx.x;
  __shared__ float BiL[NB * NP * 64];
  __shared__ float CiS[NB * NP];
  __shared__ float denomk[NP];
  __shared__ float fwL[64 * 65];

#pragma unroll
  for (int it = 0; it < 4; ++it) {
    int m = it * 1024 + t;
    fwL[(m >> 6) * 65 + (m & 63)] = fc1w[m];
  }

#pragma unroll
  for (int iter = 0; iter < 3; ++iter) {
    int m = iter * 1024 + t;  // 0..3071
    int bk = m >> 6;          // b*NP + p
    int h = m & 63;
    int b = bk / NP, p = bk - b * NP;
    int dir = h >> 5, hd = h & 31;
    const float* base = (dir == 0) ? ((p == 2) ? v : a) : ((p == 0) ? v : l);
    float q = base[(size_t)b * UU * DM + hd];
    int pb = p * NB + b;
    BiL[bk * 64 + h] = OO[(pb * 2 + dir) * DM + hd] * q;
  }
  __syncthreads();

  const int h = t & 63;
  const int g = t >> 6;  // 0..15
#pragma unroll
  for (int iter = 0; iter < 3; ++iter) {
    int bk = g + 16 * iter;
    float x = fc1b[h];
#pragma unroll 8
    for (int c = 0; c < 64; ++c)
      x = fmaf(BiL[bk * 64 + c], fwL[h * 65 + c], x);
    float vv = tanhf(x) * fc2w[h];
#pragma unroll
    for (int off = 32; off > 0; off >>= 1) vv += __shfl_down(vv, off, 64);
    if (h == 0) CiS[bk] = vv;
  }
  __syncthreads();

  if (t < NP) {
    float s = 0.f;
    for (int b = 0; b < NB; ++b) s += __expf(CiS[b * NP + t]);
    denomk[t] = s;
  }
  __syncthreads();

  {
    int b = g;
    float s = 0.f;
#pragma unroll
    for (int k = 0; k < NP; ++k)
      s += __expf(CiS[b * NP + k]) / denomk[k] * BiL[(b * NP + k) * 64 + h];
    CCA[b * 64 + h] = s;
  }
}

// ---------------------------------------------------------------------------
// Stage 4: broadcast CCA[b,:] to out[b, u, :] for all u.  float4 stores.
// (Also overwrites the S1part scratch that lived in d_out.)
// ---------------------------------------------------------------------------
__global__ __launch_bounds__(256) void stage4_bcast(
    const float* __restrict__ CCA, float4* __restrict__ out) {
  const int gid = blockIdx.x * 256 + threadIdx.x;  // 0 .. 524287
  const int c4 = gid & 15;
  const int b = gid >> 15;
  const float4* cc = (const float4*)CCA;
  out[gid] = cc[b * 16 + c4];
}

extern "C" void kernel_launch(void* const* d_in, const int* in_sizes, int n_in,
                              void* d_out, int out_size, void* d_ws,
                              size_t ws_size, hipStream_t stream) {
  const float* a = (const float*)d_in[0];
  const float* v = (const float*)d_in[1];
  const float* l = (const float*)d_in[2];
  const float* fc1w = (const float*)d_in[3];
  const float* fc1b = (const float*)d_in[4];
  const float* fc2w = (const float*)d_in[5];
  float* out = (float*)d_out;

  float* ws = (float*)d_ws;
  float* S2 = ws + WS_S2;
  float* OO = ws + WS_OO;
  float* CCA = ws + WS_CCA;
  const unsigned short* H = (const unsigned short*)(ws + WS_SPLIT);
  float* S1part = (float*)d_out;  // 6 MB scratch; stage4 overwrites last

  stage0_prep<<<dim3(1536), 256, 0, stream>>>(a, v, l, ws);
  stage1_sums<<<dim3(NP * NB * NSTRIP), 256, 0, stream>>>(H, S1part, S2);
  stage2_O<<<dim3(NP * NB * 2 * 8), 256, 0, stream>>>(a, v, l, S1part, S2, OO);
  stage3_head<<<dim3(1), 1024, 0, stream>>>(a, v, l, OO, fc1w, fc1b, fc2w,
                                            CCA);
  stage4_bcast<<<dim3(2048), 256, 0, stream>>>(CCA, (float4*)out);
}